// Round 8
// baseline (428.431 us; speedup 1.0000x reference)
//
#include <hip/hip_runtime.h>
#include <math.h>

#define N_NODES 50000
#define F_IN    512
#define HID     128
#define OUT_C   40
#define NPAD    48        // padded output cols for gemm2 MFMA
#define E_EDGES 800000
#define SCAN_BLOCKS 196   // ceil(50000/256)
#define LDA 40            // padded k-stride (bf16) for gemm1 LDS tiles
#define LDK 136           // padded k-stride (bf16) for gemm2 LDS tiles
#define MAXDEG 96         // LDS edge-stage capacity (max in-degree ~35)
#define G1B 391           // gemm1 blocks = ceil(50000/128)
#define NCHUNK 32         // edge chunks (25000 edges each)
#define NRANGE 4          // node ranges (12500 nodes each)
#define RNODES 12500
#define CHUNK_E 25000

typedef __attribute__((ext_vector_type(8))) short short8;
typedef __attribute__((ext_vector_type(4))) float f32x4;

__device__ __forceinline__ unsigned short f2bf(float f) {
    union { float f; unsigned u; } v; v.f = f;
    unsigned u = v.u + 0x7fffu + ((v.u >> 16) & 1u);   // RNE
    return (unsigned short)(u >> 16);
}
__device__ __forceinline__ float bf2f(unsigned short h) {
    return __uint_as_float((unsigned)h << 16);
}

// -------- weight prep: W1bt[n][k]=bf16(W1[k][n]); W2bt[n][k]=bf16(W2[k][n]) --------

__global__ __launch_bounds__(256) void k_wprep(const float* __restrict__ W1,
                                               const float* __restrict__ W2,
                                               unsigned short* __restrict__ W1bt,
                                               unsigned short* __restrict__ W2bt) {
    int idx = blockIdx.x * 256 + threadIdx.x;
    if (idx < F_IN * HID) {
        int k = idx & 511, n = idx >> 9;
        W1bt[(size_t)n * F_IN + k] = f2bf(W1[(size_t)k * HID + n]);
    } else if (idx < F_IN * HID + NPAD * HID) {
        int i2 = idx - F_IN * HID;
        int k = i2 & 127, n = i2 >> 7;
        W2bt[n * HID + k] = (n < OUT_C) ? f2bf(W2[(size_t)k * OUT_C + n]) : 0;
    }
}

// ------- FUSED: gemm1 (MFMA bf16, blocks [0,G1B)) + LDS-histogram pass 1 -------
// Hist blocks (chunk nc, range nr): LDS per-node pack = count<<16 | wsum_fx10.
// No global atomics anywhere; partials dumped to partial[nc][node].

__global__ __launch_bounds__(256) void k_g1hist(const float* __restrict__ X,
                                                const unsigned short* __restrict__ W1bt,
                                                unsigned short* __restrict__ Hb,
                                                const int* __restrict__ col,
                                                const float* __restrict__ ew,
                                                unsigned* __restrict__ partial) {
    __shared__ __align__(16) unsigned smem[12544];   // 50176 B
    const int tid = threadIdx.x;

    if (blockIdx.x >= G1B) {
        const int hb = blockIdx.x - G1B;            // 0..127
        const int nc = hb >> 2, nr = hb & 3;
        const int nbase = nr * RNODES;
        unsigned* cnt = smem;
        for (int i = tid; i < RNODES; i += 256) cnt[i] = 0u;
        __syncthreads();
        const int e0 = nc * CHUNK_E;
        for (int k = tid; k < CHUNK_E; k += 256) {
            int e = e0 + k;
            unsigned cr = (unsigned)(col[e] - nbase);
            if (cr < (unsigned)RNODES) {
                unsigned fx = (unsigned)(ew[e] * 1024.0f + 0.5f);
                atomicAdd(&cnt[cr], (1u << 16) | fx);
            }
        }
        __syncthreads();
        for (int i = tid; i < RNODES; i += 256)
            partial[(size_t)nc * N_NODES + nbase + i] = cnt[i];
        return;
    }

    unsigned short* As = (unsigned short*)smem;          // 128*LDA = 5120 u16
    unsigned short* Bs = As + 128 * LDA;                 // 128*LDA
    const int row0 = blockIdx.x * 128;
    const int lane = tid & 63;
    const int w    = tid >> 6;
    const int quad = lane >> 4;
    const int l16  = lane & 15;
    const int wm   = (w >> 1) * 64;
    const int wn   = (w & 1) * 64;

    f32x4 acc[4][4] = {};

    const int sr = tid >> 1;
    const int kg = (tid & 1) * 16;
    int arow = row0 + sr;
    if (arow >= N_NODES) arow = N_NODES - 1;             // clamp: rows independent
    const float*          xp = X + (size_t)arow * F_IN + kg;
    const unsigned short* bp = W1bt + (size_t)sr * F_IN + kg;
    unsigned short* asw = &As[sr * LDA + kg];
    unsigned short* bsw = &Bs[sr * LDA + kg];

    for (int k0 = 0; k0 < F_IN; k0 += 32) {
        float4 xa = *(const float4*)(xp + k0);
        float4 xb = *(const float4*)(xp + k0 + 4);
        float4 xc = *(const float4*)(xp + k0 + 8);
        float4 xd = *(const float4*)(xp + k0 + 12);
        short8 pa, pb;
        pa[0] = (short)f2bf(xa.x); pa[1] = (short)f2bf(xa.y);
        pa[2] = (short)f2bf(xa.z); pa[3] = (short)f2bf(xa.w);
        pa[4] = (short)f2bf(xb.x); pa[5] = (short)f2bf(xb.y);
        pa[6] = (short)f2bf(xb.z); pa[7] = (short)f2bf(xb.w);
        pb[0] = (short)f2bf(xc.x); pb[1] = (short)f2bf(xc.y);
        pb[2] = (short)f2bf(xc.z); pb[3] = (short)f2bf(xc.w);
        pb[4] = (short)f2bf(xd.x); pb[5] = (short)f2bf(xd.y);
        pb[6] = (short)f2bf(xd.z); pb[7] = (short)f2bf(xd.w);
        short8 wa = *(const short8*)(bp + k0);
        short8 wb = *(const short8*)(bp + k0 + 8);

        *(short8*)(asw)     = pa;
        *(short8*)(asw + 8) = pb;
        *(short8*)(bsw)     = wa;
        *(short8*)(bsw + 8) = wb;
        __syncthreads();

        short8 af[4], bf[4];
#pragma unroll
        for (int i = 0; i < 4; i++)
            af[i] = *(const short8*)&As[(wm + i * 16 + l16) * LDA + quad * 8];
#pragma unroll
        for (int j = 0; j < 4; j++)
            bf[j] = *(const short8*)&Bs[(wn + j * 16 + l16) * LDA + quad * 8];
#pragma unroll
        for (int i = 0; i < 4; i++)
#pragma unroll
            for (int j = 0; j < 4; j++)
                acc[i][j] = __builtin_amdgcn_mfma_f32_16x16x32_bf16(
                    af[i], bf[j], acc[i][j], 0, 0, 0);
        __syncthreads();
    }

#pragma unroll
    for (int i = 0; i < 4; i++) {
#pragma unroll
        for (int r = 0; r < 4; r++) {
            int grow = row0 + wm + i * 16 + quad * 4 + r;
            if (grow < N_NODES) {
#pragma unroll
                for (int j = 0; j < 4; j++) {
                    int gcol = wn + j * 16 + l16;
                    Hb[(size_t)grow * HID + gcol] = f2bf(acc[i][j][r]);
                }
            }
        }
    }
}

// ---- scan1: reduce partials -> per-node total, in-place chunk prefix, dinv ----

__global__ __launch_bounds__(256) void k_scan1(unsigned* __restrict__ partial,
                                               int* __restrict__ excl,
                                               int* __restrict__ bsum,
                                               float* __restrict__ dinv) {
    __shared__ int s[256];
    int tid = threadIdx.x;
    int i = blockIdx.x * 256 + tid;
    int v = 0;
    if (i < N_NODES) {
        unsigned ctot = 0; float wsum = 0.0f;
#pragma unroll
        for (int nc = 0; nc < NCHUNK; nc++) {
            size_t idx = (size_t)nc * N_NODES + i;
            unsigned p = partial[idx];
            partial[idx] = ctot;             // exclusive count prefix over chunks
            ctot += p >> 16;
            wsum += (float)(p & 0xffffu);
        }
        dinv[i] = rsqrtf(1.0f + wsum * (1.0f / 1024.0f));
        v = (int)ctot;
    }
    s[tid] = v;
    __syncthreads();
#pragma unroll
    for (int off = 1; off < 256; off <<= 1) {
        int t = (tid >= off) ? s[tid - off] : 0;
        __syncthreads();
        s[tid] += t;
        __syncthreads();
    }
    if (i < N_NODES) excl[i] = s[tid] - v;
    if (tid == 255) bsum[blockIdx.x] = s[255];
}

__global__ __launch_bounds__(256) void k_scan2(int* __restrict__ bsum) {
    __shared__ int s[256];
    int tid = threadIdx.x;
    int v = (tid < SCAN_BLOCKS) ? bsum[tid] : 0;
    s[tid] = v;
    __syncthreads();
#pragma unroll
    for (int off = 1; off < 256; off <<= 1) {
        int t = (tid >= off) ? s[tid - off] : 0;
        __syncthreads();
        s[tid] += t;
        __syncthreads();
    }
    if (tid < SCAN_BLOCKS) bsum[tid] = s[tid] - v;   // exclusive
}

// ---- scan3: finalize rowptr AND absolutize chunk bases (cbabs = cb + rowptr) ----

__global__ __launch_bounds__(256) void k_scan3(int* __restrict__ rowptr,
                                               const int* __restrict__ bsum,
                                               unsigned* __restrict__ partial) {
    int i = blockIdx.x * 256 + threadIdx.x;
    if (i < N_NODES) {
        int rp = rowptr[i] + bsum[blockIdx.x];
        rowptr[i] = rp;
#pragma unroll
        for (int nc = 0; nc < NCHUNK; nc++)
            partial[(size_t)nc * N_NODES + i] += (unsigned)rp;
    }
    if (i == 0) rowptr[N_NODES] = E_EDGES;
}

// ---- pass 2: LDS local ranks -> scatter es=(src, dinv[src]*w), no atomics ----

__global__ __launch_bounds__(256) void k_scatter2(const int* __restrict__ row,
                                                  const int* __restrict__ col,
                                                  const float* __restrict__ ew,
                                                  const float* __restrict__ dinv,
                                                  const unsigned* __restrict__ cbabs,
                                                  int2* __restrict__ es) {
    __shared__ unsigned cnt[RNODES];
    const int tid = threadIdx.x;
    const int nc = blockIdx.x >> 2, nr = blockIdx.x & 3;
    const int nbase = nr * RNODES;
    for (int i = tid; i < RNODES; i += 256) cnt[i] = 0u;
    __syncthreads();
    const int e0 = nc * CHUNK_E;
    for (int k = tid; k < CHUNK_E; k += 256) {
        int e = e0 + k;
        int c = col[e];
        unsigned cr = (unsigned)(c - nbase);
        if (cr < (unsigned)RNODES) {
            unsigned local = atomicAdd(&cnt[cr], 1u);
            unsigned pos = cbabs[(size_t)nc * N_NODES + c] + local;
            int r = row[e];
            float pre = dinv[r] * ew[e];
            es[pos] = make_int2(r, __float_as_int(pre));
        }
    }
}

// ------- CSR agg layer 1 on bf16 H1, bf16 A1 out: one wave/node, 2 cols/thread -------

__global__ __launch_bounds__(256) void k_agg1_csr(const int* __restrict__ rowptr,
                                                  const int2* __restrict__ es,
                                                  const float* __restrict__ dinv,
                                                  const unsigned short* __restrict__ H1b,
                                                  const float* __restrict__ b1,
                                                  unsigned short* __restrict__ A1b) {
    __shared__ int2 sE[4][MAXDEG];
    const int tid  = threadIdx.x;
    const int wv   = tid >> 6;
    const int lane = tid & 63;
    const int node = blockIdx.x * 4 + wv;          // 50000 % 4 == 0
    if (node >= N_NODES) return;

    const int beg = rowptr[node];
    const int d   = rowptr[node + 1] - beg;
    const int dl  = (d < MAXDEG) ? d : MAXDEG;
    const int dp  = (dl + 7) & ~7;
    for (int p = lane; p < dp; p += 64)
        sE[wv][p] = (p < dl) ? es[beg + p] : make_int2(0, 0);
    // wave-private LDS region: compiler-inserted lgkmcnt wait suffices

    const float di = dinv[node];
    const unsigned self = *(const unsigned*)&H1b[(size_t)node * HID + lane * 2];
    float al0 = di * __uint_as_float(self << 16);
    float ah0 = di * __uint_as_float(self & 0xffff0000u);
    float al1 = 0.0f, ah1 = 0.0f, al2 = 0.0f, ah2 = 0.0f, al3 = 0.0f, ah3 = 0.0f;

    for (int p = 0; p < dp; p += 8) {
        int s[8]; float n[8]; unsigned g[8];
#pragma unroll
        for (int j = 0; j < 8; j++) {
            int2 t = sE[wv][p + j];
            s[j] = t.x; n[j] = __int_as_float(t.y);
        }
#pragma unroll
        for (int j = 0; j < 8; j++)
            g[j] = *(const unsigned*)&H1b[(size_t)s[j] * HID + lane * 2];
        al0 = fmaf(__uint_as_float(g[0] << 16), n[0], al0);
        ah0 = fmaf(__uint_as_float(g[0] & 0xffff0000u), n[0], ah0);
        al1 = fmaf(__uint_as_float(g[1] << 16), n[1], al1);
        ah1 = fmaf(__uint_as_float(g[1] & 0xffff0000u), n[1], ah1);
        al2 = fmaf(__uint_as_float(g[2] << 16), n[2], al2);
        ah2 = fmaf(__uint_as_float(g[2] & 0xffff0000u), n[2], ah2);
        al3 = fmaf(__uint_as_float(g[3] << 16), n[3], al3);
        ah3 = fmaf(__uint_as_float(g[3] & 0xffff0000u), n[3], ah3);
        al0 = fmaf(__uint_as_float(g[4] << 16), n[4], al0);
        ah0 = fmaf(__uint_as_float(g[4] & 0xffff0000u), n[4], ah0);
        al1 = fmaf(__uint_as_float(g[5] << 16), n[5], al1);
        ah1 = fmaf(__uint_as_float(g[5] & 0xffff0000u), n[5], ah1);
        al2 = fmaf(__uint_as_float(g[6] << 16), n[6], al2);
        ah2 = fmaf(__uint_as_float(g[6] & 0xffff0000u), n[6], ah2);
        al3 = fmaf(__uint_as_float(g[7] << 16), n[7], al3);
        ah3 = fmaf(__uint_as_float(g[7] & 0xffff0000u), n[7], ah3);
    }
    for (int q = dl; q < d; ++q) {   // overflow fallback (never hit in practice)
        int2 t = es[beg + q];
        unsigned g = *(const unsigned*)&H1b[(size_t)t.x * HID + lane * 2];
        float nm = __int_as_float(t.y);
        al0 = fmaf(__uint_as_float(g << 16), nm, al0);
        ah0 = fmaf(__uint_as_float(g & 0xffff0000u), nm, ah0);
    }

    const float accl = (al0 + al1) + (al2 + al3);
    const float acch = (ah0 + ah1) + (ah2 + ah3);
    const int c = lane * 2;
    float rx = fmaxf(fmaf(di, accl, b1[c]), 0.0f);
    float ry = fmaxf(fmaf(di, acch, b1[c + 1]), 0.0f);
    unsigned pack = (unsigned)f2bf(rx) | ((unsigned)f2bf(ry) << 16);
    *(unsigned*)&A1b[(size_t)node * HID + c] = pack;
}

// ------- GEMM2 (MFMA bf16): H2b[50000,48] = A1b[50000,128] @ W2bt^T -------

__global__ __launch_bounds__(256) void k_gemm2_mfma(const unsigned short* __restrict__ A1b,
                                                    const unsigned short* __restrict__ W2bt,
                                                    unsigned short* __restrict__ H2b) {
    __shared__ __align__(16) unsigned short As[128 * LDK];
    __shared__ __align__(16) unsigned short Bs[NPAD * LDK];
    const int tid  = threadIdx.x;
    const int row0 = blockIdx.x * 128;
    const int lane = tid & 63;
    const int w    = tid >> 6;
    const int quad = lane >> 4;
    const int l16  = lane & 15;

#pragma unroll
    for (int i = 0; i < 8; i++) {
        int id = tid + i * 256;
        int r = id >> 4, kc = (id & 15) * 8;
        int ar = row0 + r; if (ar >= N_NODES) ar = N_NODES - 1;
        *(short8*)&As[r * LDK + kc] = *(const short8*)&A1b[(size_t)ar * HID + kc];
    }
#pragma unroll
    for (int i = 0; i < 3; i++) {
        int id = tid + i * 256;
        int n = id >> 4, kc = (id & 15) * 8;
        *(short8*)&Bs[n * LDK + kc] = *(const short8*)&W2bt[n * HID + kc];
    }
    __syncthreads();

    f32x4 acc[2][3] = {};
    const int rbase = w * 32;
#pragma unroll
    for (int ks = 0; ks < 4; ks++) {
        const int k0 = ks * 32 + quad * 8;
        short8 af[2], bf[3];
#pragma unroll
        for (int i = 0; i < 2; i++)
            af[i] = *(const short8*)&As[(rbase + i * 16 + l16) * LDK + k0];
#pragma unroll
        for (int j = 0; j < 3; j++)
            bf[j] = *(const short8*)&Bs[(j * 16 + l16) * LDK + k0];
#pragma unroll
        for (int i = 0; i < 2; i++)
#pragma unroll
            for (int j = 0; j < 3; j++)
                acc[i][j] = __builtin_amdgcn_mfma_f32_16x16x32_bf16(
                    af[i], bf[j], acc[i][j], 0, 0, 0);
    }

#pragma unroll
    for (int i = 0; i < 2; i++) {
#pragma unroll
        for (int r = 0; r < 4; r++) {
            int grow = row0 + rbase + i * 16 + quad * 4 + r;
            if (grow < N_NODES) {
#pragma unroll
                for (int j = 0; j < 3; j++)
                    H2b[(size_t)grow * NPAD + j * 16 + l16] = f2bf(acc[i][j][r]);
            }
        }
    }
}

// ------- CSR agg layer 2 (bf16 H2b) + bias fused with log_softmax -------

__global__ __launch_bounds__(256) void k_agg2_lsm(const int* __restrict__ rowptr,
                                                  const int2* __restrict__ es,
                                                  const float* __restrict__ dinv,
                                                  const unsigned short* __restrict__ H2b,
                                                  const float* __restrict__ b2,
                                                  float* __restrict__ out) {
    __shared__ int2 sE[4][MAXDEG];
    const int tid  = threadIdx.x;
    const int wv   = tid >> 6;
    const int lane = tid & 63;
    const int node = blockIdx.x * 4 + wv;
    if (node >= N_NODES) return;

    const int beg = rowptr[node];
    const int d   = rowptr[node + 1] - beg;
    const int dl = (d < MAXDEG) ? d : MAXDEG;
    const int dp = (dl + 7) & ~7;
    for (int p = lane; p < dp; p += 64)
        sE[wv][p] = (p < dl) ? es[beg + p] : make_int2(0, 0);
    // wave-private LDS region

    float di = dinv[node];
    float a0 = 0.0f, a1 = 0.0f, a2 = 0.0f, a3 = 0.0f;
    if (lane < OUT_C) a0 = di * bf2f(H2b[(size_t)node * NPAD + lane]);

    for (int p = 0; p < dp; p += 8) {
        int s[8]; float n[8], v[8];
#pragma unroll
        for (int j = 0; j < 8; j++) {
            int2 t = sE[wv][p + j];
            s[j] = t.x; n[j] = __int_as_float(t.y);
        }
#pragma unroll
        for (int j = 0; j < 8; j++)
            v[j] = (lane < OUT_C) ? bf2f(H2b[(size_t)s[j] * NPAD + lane]) : 0.0f;
        a0 = fmaf(v[0], n[0], a0);  a1 = fmaf(v[1], n[1], a1);
        a2 = fmaf(v[2], n[2], a2);  a3 = fmaf(v[3], n[3], a3);
        a0 = fmaf(v[4], n[4], a0);  a1 = fmaf(v[5], n[5], a1);
        a2 = fmaf(v[6], n[6], a2);  a3 = fmaf(v[7], n[7], a3);
    }
    for (int q = dl; q < d; ++q)   // overflow fallback
        if (lane < OUT_C) {
            int2 t = es[beg + q];
            a0 = fmaf(bf2f(H2b[(size_t)t.x * NPAD + lane]), __int_as_float(t.y), a0);
        }

    float acc = (a0 + a1) + (a2 + a3);
    float v = (lane < OUT_C) ? fmaf(di, acc, b2[lane]) : -INFINITY;

    float m = v;
#pragma unroll
    for (int off = 32; off > 0; off >>= 1) m = fmaxf(m, __shfl_xor(m, off));
    float ex = (lane < OUT_C) ? __expf(v - m) : 0.0f;
    float s = ex;
#pragma unroll
    for (int off = 32; off > 0; off >>= 1) s += __shfl_xor(s, off);
    if (lane < OUT_C) out[(size_t)node * OUT_C + lane] = v - m - __logf(s);
}

// ---------------- launch ----------------

extern "C" void kernel_launch(void* const* d_in, const int* in_sizes, int n_in,
                              void* d_out, int out_size, void* d_ws, size_t ws_size,
                              hipStream_t stream) {
    const float* x  = (const float*)d_in[0];
    const int*   ei = (const int*)d_in[1];          // [2, E] int32
    const float* ew = (const float*)d_in[2];
    const float* W1 = (const float*)d_in[3];
    const float* b1 = (const float*)d_in[4];
    const float* W2 = (const float*)d_in[5];
    const float* b2 = (const float*)d_in[6];
    float* out = (float*)d_out;

    const int* row = ei;            // sources
    const int* col = ei + E_EDGES;  // targets

    // workspace layout (float units), ~43.7 MB, no aliasing
    float* ws = (float*)d_ws;
    unsigned* partial = (unsigned*)ws;                         // [0, 1600000) 32x50000 u32
    float* dinv   = ws + 1600000;                              // 50000
    int*   rowptr = (int*)(ws + 1650016);                      // 50001
    int*   bsum   = (int*)(ws + 1700032);                      // 256
    int2*  es     = (int2*)(ws + 1700352);                     // E int2 (16B-aligned)
    unsigned short* H1b  = (unsigned short*)(ws + 3300352);    // N*HID bf16
    unsigned short* A1b  = (unsigned short*)(ws + 6500352);    // N*HID bf16
    unsigned short* W1bt = (unsigned short*)(ws + 9700352);    // 128*512 bf16
    unsigned short* W2bt = (unsigned short*)(ws + 9733120);    // 48*128 bf16
    unsigned short* H2b  = (unsigned short*)(ws + 9736192);    // N*48 bf16

    const int B = 256;

    k_wprep<<<(F_IN * HID + NPAD * HID + B - 1) / B, B, 0, stream>>>(W1, W2, W1bt, W2bt);

    k_g1hist<<<G1B + NCHUNK * NRANGE, B, 0, stream>>>(x, W1bt, H1b, col, ew, partial);

    k_scan1<<<SCAN_BLOCKS, B, 0, stream>>>(partial, rowptr, bsum, dinv);
    k_scan2<<<1, B, 0, stream>>>(bsum);
    k_scan3<<<SCAN_BLOCKS, B, 0, stream>>>(rowptr, bsum, partial);

    k_scatter2<<<NCHUNK * NRANGE, B, 0, stream>>>(row, col, ew, dinv, partial, es);

    k_agg1_csr<<<(N_NODES + 3) / 4, B, 0, stream>>>(rowptr, es, dinv, H1b, b1, A1b);

    k_gemm2_mfma<<<(N_NODES + 127) / 128, B, 0, stream>>>(A1b, W2bt, H2b);

    k_agg2_lsm<<<(N_NODES + 3) / 4, B, 0, stream>>>(rowptr, es, dinv, H2b, b2, out);
}

// Round 10
// 333.770 us; speedup vs baseline: 1.2836x; 1.2836x over previous
//
#include <hip/hip_runtime.h>
#include <math.h>

#define N_NODES 50000
#define F_IN    512
#define HID     128
#define OUT_C   40
#define NPAD    48        // padded output cols for gemm2 MFMA
#define E_EDGES 800000
#define SCAN_BLOCKS 196   // ceil(50000/256)
#define LDA 40            // padded k-stride (bf16) for gemm1 LDS tiles
#define LDK 136           // padded k-stride (bf16) for gemm2 LDS tiles
#define MAXDEG 96         // LDS edge-stage capacity (max in-degree ~35)
#define G1B 391           // gemm1 blocks = ceil(50000/128)
#define DEGB 782          // deg blocks: 4 edges/thread -> ceil(800000/1024)
#define SCATB 782         // scatter blocks, same batching

typedef __attribute__((ext_vector_type(8))) short short8;
typedef __attribute__((ext_vector_type(4))) float f32x4;   // native clang vector

__device__ __forceinline__ unsigned short f2bf(float f) {
    union { float f; unsigned u; } v; v.f = f;
    unsigned u = v.u + 0x7fffu + ((v.u >> 16) & 1u);   // RNE
    return (unsigned short)(u >> 16);
}
__device__ __forceinline__ float bf2f(unsigned short h) {
    return __uint_as_float((unsigned)h << 16);
}

// -------- weight prep + packed-histogram zeroing (fused grids) --------

__global__ __launch_bounds__(256) void k_wprep(const float* __restrict__ W1,
                                               const float* __restrict__ W2,
                                               unsigned short* __restrict__ W1bt,
                                               unsigned short* __restrict__ W2bt,
                                               unsigned long long* __restrict__ packed) {
    int idx = blockIdx.x * 256 + threadIdx.x;
    if (idx < F_IN * HID) {
        int k = idx & 511, n = idx >> 9;
        W1bt[(size_t)n * F_IN + k] = f2bf(W1[(size_t)k * HID + n]);
    } else if (idx < F_IN * HID + NPAD * HID) {
        int i2 = idx - F_IN * HID;
        int k = i2 & 127, n = i2 >> 7;
        W2bt[n * HID + k] = (n < OUT_C) ? f2bf(W2[(size_t)k * OUT_C + n]) : 0;
    } else {
        int i3 = idx - (F_IN * HID + NPAD * HID);
        if (i3 < N_NODES) packed[i3] = 0ULL;
    }
}

// ------- FUSED: gemm1 (MFMA bf16, blocks [0,G1B)) + deg/cnt/rank (rest) -------
// packed[c]: [63:40]=count, [39:0]=sum(w)*2^32. Atomic return gives edge rank.
// Deg branch: 4 edges/thread (4 atomics in flight). X/col/ew loads nontemporal
// (zero-reuse streams; keep them out of L2 which the atomics need).

__global__ __launch_bounds__(256) void k_g1deg(const float* __restrict__ X,
                                               const unsigned short* __restrict__ W1bt,
                                               unsigned short* __restrict__ Hb,
                                               const int* __restrict__ col,
                                               const float* __restrict__ ew,
                                               unsigned long long* __restrict__ packed,
                                               int* __restrict__ rank) {
    const int tid = threadIdx.x;
    if (blockIdx.x >= G1B) {
        const int e0 = (blockIdx.x - G1B) * 1024 + tid;
        unsigned long long old[4];
#pragma unroll
        for (int j = 0; j < 4; j++) {
            int e = e0 + j * 256;
            if (e < E_EDGES) {
                int c = __builtin_nontemporal_load(col + e);
                float w = __builtin_nontemporal_load(ew + e);
                unsigned long long fx = (unsigned long long)(w * 4294967296.0f);
                old[j] = atomicAdd(&packed[c], (1ULL << 40) | fx);
            }
        }
#pragma unroll
        for (int j = 0; j < 4; j++) {
            int e = e0 + j * 256;
            if (e < E_EDGES) rank[e] = (int)(old[j] >> 40);
        }
        return;
    }

    __shared__ __align__(16) unsigned short As[128 * LDA];
    __shared__ __align__(16) unsigned short Bs[128 * LDA];
    const int row0 = blockIdx.x * 128;
    const int lane = tid & 63;
    const int w    = tid >> 6;
    const int quad = lane >> 4;
    const int l16  = lane & 15;
    const int wm   = (w >> 1) * 64;
    const int wn   = (w & 1) * 64;

    f32x4 acc[4][4] = {};

    const int sr = tid >> 1;
    const int kg = (tid & 1) * 16;
    int arow = row0 + sr;
    if (arow >= N_NODES) arow = N_NODES - 1;          // clamp: rows independent
    const float*          xp = X + (size_t)arow * F_IN + kg;
    const unsigned short* bp = W1bt + (size_t)sr * F_IN + kg;
    unsigned short* asw = &As[sr * LDA + kg];
    unsigned short* bsw = &Bs[sr * LDA + kg];

    for (int k0 = 0; k0 < F_IN; k0 += 32) {
        f32x4 xa = __builtin_nontemporal_load((const f32x4*)(xp + k0));
        f32x4 xb = __builtin_nontemporal_load((const f32x4*)(xp + k0 + 4));
        f32x4 xc = __builtin_nontemporal_load((const f32x4*)(xp + k0 + 8));
        f32x4 xd = __builtin_nontemporal_load((const f32x4*)(xp + k0 + 12));
        short8 pa, pb;
        pa[0] = (short)f2bf(xa.x); pa[1] = (short)f2bf(xa.y);
        pa[2] = (short)f2bf(xa.z); pa[3] = (short)f2bf(xa.w);
        pa[4] = (short)f2bf(xb.x); pa[5] = (short)f2bf(xb.y);
        pa[6] = (short)f2bf(xb.z); pa[7] = (short)f2bf(xb.w);
        pb[0] = (short)f2bf(xc.x); pb[1] = (short)f2bf(xc.y);
        pb[2] = (short)f2bf(xc.z); pb[3] = (short)f2bf(xc.w);
        pb[4] = (short)f2bf(xd.x); pb[5] = (short)f2bf(xd.y);
        pb[6] = (short)f2bf(xd.z); pb[7] = (short)f2bf(xd.w);
        short8 wa = *(const short8*)(bp + k0);
        short8 wb = *(const short8*)(bp + k0 + 8);

        *(short8*)(asw)     = pa;
        *(short8*)(asw + 8) = pb;
        *(short8*)(bsw)     = wa;
        *(short8*)(bsw + 8) = wb;
        __syncthreads();

        short8 af[4], bf[4];
#pragma unroll
        for (int i = 0; i < 4; i++)
            af[i] = *(const short8*)&As[(wm + i * 16 + l16) * LDA + quad * 8];
#pragma unroll
        for (int j = 0; j < 4; j++)
            bf[j] = *(const short8*)&Bs[(wn + j * 16 + l16) * LDA + quad * 8];
#pragma unroll
        for (int i = 0; i < 4; i++)
#pragma unroll
            for (int j = 0; j < 4; j++)
                acc[i][j] = __builtin_amdgcn_mfma_f32_16x16x32_bf16(
                    af[i], bf[j], acc[i][j], 0, 0, 0);
        __syncthreads();
    }

#pragma unroll
    for (int i = 0; i < 4; i++) {
#pragma unroll
        for (int r = 0; r < 4; r++) {
            int grow = row0 + wm + i * 16 + quad * 4 + r;
            if (grow < N_NODES) {
#pragma unroll
                for (int j = 0; j < 4; j++) {
                    int gcol = wn + j * 16 + l16;
                    Hb[(size_t)grow * HID + gcol] = f2bf(acc[i][j][r]);
                }
            }
        }
    }
}

// ---------------- scan stage 1 (+ fused dinv) ----------------

__global__ __launch_bounds__(256) void k_scan1(const unsigned long long* __restrict__ packed,
                                               int* __restrict__ excl,
                                               int* __restrict__ bsum,
                                               float* __restrict__ dinv) {
    __shared__ int s[256];
    int tid = threadIdx.x;
    int i = blockIdx.x * 256 + tid;
    unsigned long long pk = (i < N_NODES) ? packed[i] : 0ULL;
    int v = (int)(pk >> 40);
    if (i < N_NODES) {
        float d = 1.0f + (float)(pk & 0xFFFFFFFFFFULL) * (1.0f / 4294967296.0f);
        dinv[i] = rsqrtf(d);    // d >= 1 (self-loop)
    }
    s[tid] = v;
    __syncthreads();
#pragma unroll
    for (int off = 1; off < 256; off <<= 1) {
        int t = (tid >= off) ? s[tid - off] : 0;
        __syncthreads();
        s[tid] += t;
        __syncthreads();
    }
    if (i < N_NODES) excl[i] = s[tid] - v;
    if (tid == 255) bsum[blockIdx.x] = s[255];
}

// ---- scan3 (scan2 folded in): each block redundantly scans the 196 bsums ----

__global__ __launch_bounds__(256) void k_scan3(int* __restrict__ rowptr,
                                               const int* __restrict__ bsum) {
    __shared__ int s[256];
    int tid = threadIdx.x;
    int v = (tid < SCAN_BLOCKS) ? bsum[tid] : 0;
    s[tid] = v;
    __syncthreads();
#pragma unroll
    for (int off = 1; off < 256; off <<= 1) {
        int t = (tid >= off) ? s[tid - off] : 0;
        __syncthreads();
        s[tid] += t;
        __syncthreads();
    }
    int base = s[blockIdx.x] - ((blockIdx.x < SCAN_BLOCKS) ? bsum[blockIdx.x] : 0);
    int i = blockIdx.x * 256 + tid;
    if (i < N_NODES) rowptr[i] += base;
    if (i == 0) rowptr[N_NODES] = E_EDGES;
}

// ------- scatter into CSR order, atomic-free, 4 edges/thread; pre=dinv[src]*w -------

__global__ __launch_bounds__(256) void k_scatter(const int* __restrict__ row,
                                                 const int* __restrict__ col,
                                                 const float* __restrict__ ew,
                                                 const float* __restrict__ dinv,
                                                 const int* __restrict__ rowptr,
                                                 const int* __restrict__ rank,
                                                 int2* __restrict__ es) {
    const int e0 = blockIdx.x * 1024 + threadIdx.x;
#pragma unroll
    for (int j = 0; j < 4; j++) {
        int e = e0 + j * 256;
        if (e < E_EDGES) {
            int r = row[e], c = col[e];
            float pre = dinv[r] * ew[e];
            int pos = rowptr[c] + rank[e];
            es[pos] = make_int2(r, __float_as_int(pre));
        }
    }
}

// ------- CSR agg layer 1 on bf16 H1, bf16 A1 out: one wave/node, 2 cols/thread -------

__global__ __launch_bounds__(256) void k_agg1_csr(const int* __restrict__ rowptr,
                                                  const int2* __restrict__ es,
                                                  const float* __restrict__ dinv,
                                                  const unsigned short* __restrict__ H1b,
                                                  const float* __restrict__ b1,
                                                  unsigned short* __restrict__ A1b) {
    __shared__ int2 sE[4][MAXDEG];
    const int tid  = threadIdx.x;
    const int wv   = tid >> 6;
    const int lane = tid & 63;
    const int node = blockIdx.x * 4 + wv;          // 50000 % 4 == 0
    if (node >= N_NODES) return;

    const int beg = rowptr[node];
    const int d   = rowptr[node + 1] - beg;
    const int dl  = (d < MAXDEG) ? d : MAXDEG;
    const int dp  = (dl + 7) & ~7;
    for (int p = lane; p < dp; p += 64)
        sE[wv][p] = (p < dl) ? es[beg + p] : make_int2(0, 0);
    // wave-private LDS region: compiler-inserted lgkmcnt wait suffices

    const float di = dinv[node];
    const unsigned self = *(const unsigned*)&H1b[(size_t)node * HID + lane * 2];
    float al0 = di * __uint_as_float(self << 16);
    float ah0 = di * __uint_as_float(self & 0xffff0000u);
    float al1 = 0.0f, ah1 = 0.0f, al2 = 0.0f, ah2 = 0.0f, al3 = 0.0f, ah3 = 0.0f;

    for (int p = 0; p < dp; p += 8) {
        int s[8]; float n[8]; unsigned g[8];
#pragma unroll
        for (int j = 0; j < 8; j++) {
            int2 t = sE[wv][p + j];
            s[j] = t.x; n[j] = __int_as_float(t.y);
        }
#pragma unroll
        for (int j = 0; j < 8; j++)
            g[j] = *(const unsigned*)&H1b[(size_t)s[j] * HID + lane * 2];
        al0 = fmaf(__uint_as_float(g[0] << 16), n[0], al0);
        ah0 = fmaf(__uint_as_float(g[0] & 0xffff0000u), n[0], ah0);
        al1 = fmaf(__uint_as_float(g[1] << 16), n[1], al1);
        ah1 = fmaf(__uint_as_float(g[1] & 0xffff0000u), n[1], ah1);
        al2 = fmaf(__uint_as_float(g[2] << 16), n[2], al2);
        ah2 = fmaf(__uint_as_float(g[2] & 0xffff0000u), n[2], ah2);
        al3 = fmaf(__uint_as_float(g[3] << 16), n[3], al3);
        ah3 = fmaf(__uint_as_float(g[3] & 0xffff0000u), n[3], ah3);
        al0 = fmaf(__uint_as_float(g[4] << 16), n[4], al0);
        ah0 = fmaf(__uint_as_float(g[4] & 0xffff0000u), n[4], ah0);
        al1 = fmaf(__uint_as_float(g[5] << 16), n[5], al1);
        ah1 = fmaf(__uint_as_float(g[5] & 0xffff0000u), n[5], ah1);
        al2 = fmaf(__uint_as_float(g[6] << 16), n[6], al2);
        ah2 = fmaf(__uint_as_float(g[6] & 0xffff0000u), n[6], ah2);
        al3 = fmaf(__uint_as_float(g[7] << 16), n[7], al3);
        ah3 = fmaf(__uint_as_float(g[7] & 0xffff0000u), n[7], ah3);
    }
    for (int q = dl; q < d; ++q) {   // overflow fallback (never hit in practice)
        int2 t = es[beg + q];
        unsigned g = *(const unsigned*)&H1b[(size_t)t.x * HID + lane * 2];
        float nm = __int_as_float(t.y);
        al0 = fmaf(__uint_as_float(g << 16), nm, al0);
        ah0 = fmaf(__uint_as_float(g & 0xffff0000u), nm, ah0);
    }

    const float accl = (al0 + al1) + (al2 + al3);
    const float acch = (ah0 + ah1) + (ah2 + ah3);
    const int c = lane * 2;
    float rx = fmaxf(fmaf(di, accl, b1[c]), 0.0f);
    float ry = fmaxf(fmaf(di, acch, b1[c + 1]), 0.0f);
    unsigned pack = (unsigned)f2bf(rx) | ((unsigned)f2bf(ry) << 16);
    *(unsigned*)&A1b[(size_t)node * HID + c] = pack;
}

// ------- GEMM2 (MFMA bf16): H2b[50000,48] = A1b[50000,128] @ W2bt^T -------

__global__ __launch_bounds__(256) void k_gemm2_mfma(const unsigned short* __restrict__ A1b,
                                                    const unsigned short* __restrict__ W2bt,
                                                    unsigned short* __restrict__ H2b) {
    __shared__ __align__(16) unsigned short As[128 * LDK];
    __shared__ __align__(16) unsigned short Bs[NPAD * LDK];
    const int tid  = threadIdx.x;
    const int row0 = blockIdx.x * 128;
    const int lane = tid & 63;
    const int w    = tid >> 6;
    const int quad = lane >> 4;
    const int l16  = lane & 15;

#pragma unroll
    for (int i = 0; i < 8; i++) {
        int id = tid + i * 256;
        int r = id >> 4, kc = (id & 15) * 8;
        int ar = row0 + r; if (ar >= N_NODES) ar = N_NODES - 1;
        *(short8*)&As[r * LDK + kc] = *(const short8*)&A1b[(size_t)ar * HID + kc];
    }
#pragma unroll
    for (int i = 0; i < 3; i++) {
        int id = tid + i * 256;
        int n = id >> 4, kc = (id & 15) * 8;
        *(short8*)&Bs[n * LDK + kc] = *(const short8*)&W2bt[n * HID + kc];
    }
    __syncthreads();

    f32x4 acc[2][3] = {};
    const int rbase = w * 32;
#pragma unroll
    for (int ks = 0; ks < 4; ks++) {
        const int k0 = ks * 32 + quad * 8;
        short8 af[2], bf[3];
#pragma unroll
        for (int i = 0; i < 2; i++)
            af[i] = *(const short8*)&As[(rbase + i * 16 + l16) * LDK + k0];
#pragma unroll
        for (int j = 0; j < 3; j++)
            bf[j] = *(const short8*)&Bs[(j * 16 + l16) * LDK + k0];
#pragma unroll
        for (int i = 0; i < 2; i++)
#pragma unroll
            for (int j = 0; j < 3; j++)
                acc[i][j] = __builtin_amdgcn_mfma_f32_16x16x32_bf16(
                    af[i], bf[j], acc[i][j], 0, 0, 0);
    }

#pragma unroll
    for (int i = 0; i < 2; i++) {
#pragma unroll
        for (int r = 0; r < 4; r++) {
            int grow = row0 + rbase + i * 16 + quad * 4 + r;
            if (grow < N_NODES) {
#pragma unroll
                for (int j = 0; j < 3; j++)
                    H2b[(size_t)grow * NPAD + j * 16 + l16] = f2bf(acc[i][j][r]);
            }
        }
    }
}

// ------- CSR agg layer 2 (bf16 H2b) + bias fused with log_softmax -------

__global__ __launch_bounds__(256) void k_agg2_lsm(const int* __restrict__ rowptr,
                                                  const int2* __restrict__ es,
                                                  const float* __restrict__ dinv,
                                                  const unsigned short* __restrict__ H2b,
                                                  const float* __restrict__ b2,
                                                  float* __restrict__ out) {
    __shared__ int2 sE[4][MAXDEG];
    const int tid  = threadIdx.x;
    const int wv   = tid >> 6;
    const int lane = tid & 63;
    const int node = blockIdx.x * 4 + wv;
    if (node >= N_NODES) return;

    const int beg = rowptr[node];
    const int d   = rowptr[node + 1] - beg;
    const int dl = (d < MAXDEG) ? d : MAXDEG;
    const int dp = (dl + 7) & ~7;
    for (int p = lane; p < dp; p += 64)
        sE[wv][p] = (p < dl) ? es[beg + p] : make_int2(0, 0);
    // wave-private LDS region

    float di = dinv[node];
    float a0 = 0.0f, a1 = 0.0f, a2 = 0.0f, a3 = 0.0f;
    if (lane < OUT_C) a0 = di * bf2f(H2b[(size_t)node * NPAD + lane]);

    for (int p = 0; p < dp; p += 8) {
        int s[8]; float n[8], v[8];
#pragma unroll
        for (int j = 0; j < 8; j++) {
            int2 t = sE[wv][p + j];
            s[j] = t.x; n[j] = __int_as_float(t.y);
        }
#pragma unroll
        for (int j = 0; j < 8; j++)
            v[j] = (lane < OUT_C) ? bf2f(H2b[(size_t)s[j] * NPAD + lane]) : 0.0f;
        a0 = fmaf(v[0], n[0], a0);  a1 = fmaf(v[1], n[1], a1);
        a2 = fmaf(v[2], n[2], a2);  a3 = fmaf(v[3], n[3], a3);
        a0 = fmaf(v[4], n[4], a0);  a1 = fmaf(v[5], n[5], a1);
        a2 = fmaf(v[6], n[6], a2);  a3 = fmaf(v[7], n[7], a3);
    }
    for (int q = dl; q < d; ++q)   // overflow fallback
        if (lane < OUT_C) {
            int2 t = es[beg + q];
            a0 = fmaf(bf2f(H2b[(size_t)t.x * NPAD + lane]), __int_as_float(t.y), a0);
        }

    float acc = (a0 + a1) + (a2 + a3);
    float v = (lane < OUT_C) ? fmaf(di, acc, b2[lane]) : -INFINITY;

    float m = v;
#pragma unroll
    for (int off = 32; off > 0; off >>= 1) m = fmaxf(m, __shfl_xor(m, off));
    float ex = (lane < OUT_C) ? __expf(v - m) : 0.0f;
    float s = ex;
#pragma unroll
    for (int off = 32; off > 0; off >>= 1) s += __shfl_xor(s, off);
    if (lane < OUT_C) out[(size_t)node * OUT_C + lane] = v - m - __logf(s);
}

// ---------------- launch ----------------

extern "C" void kernel_launch(void* const* d_in, const int* in_sizes, int n_in,
                              void* d_out, int out_size, void* d_ws, size_t ws_size,
                              hipStream_t stream) {
    const float* x  = (const float*)d_in[0];
    const int*   ei = (const int*)d_in[1];          // [2, E] int32
    const float* ew = (const float*)d_in[2];
    const float* W1 = (const float*)d_in[3];
    const float* b1 = (const float*)d_in[4];
    const float* W2 = (const float*)d_in[5];
    const float* b2 = (const float*)d_in[6];
    float* out = (float*)d_out;

    const int* row = ei;            // sources
    const int* col = ei + E_EDGES;  // targets

    // workspace layout (float units), ~41 MB, no aliasing
    float* ws = (float*)d_ws;
    unsigned long long* packed = (unsigned long long*)ws;          // [0, 100000)
    float* dinv   = ws + 100000;                                   // 50000
    int*   rowptr = (int*)(ws + 150000);                           // 50001
    int*   bsum   = (int*)(ws + 200016);                           // 256
    int2*  es     = (int2*)(ws + 200272);                          // E int2
    int*   rank   = (int*)(ws + 1800272);                          // E
    unsigned short* H1b  = (unsigned short*)(ws + 2600272);        // N*HID bf16
    unsigned short* A1b  = (unsigned short*)(ws + 5800272);        // N*HID bf16
    unsigned short* W1bt = (unsigned short*)(ws + 9000272);        // 128*512 bf16
    unsigned short* W2bt = (unsigned short*)(ws + 9033040);        // 48*128 bf16
    unsigned short* H2b  = (unsigned short*)(ws + 9036112);        // N*48 bf16

    const int B = 256;

    k_wprep<<<(F_IN * HID + NPAD * HID + N_NODES + B - 1) / B, B, 0, stream>>>(
        W1, W2, W1bt, W2bt, packed);

    k_g1deg<<<G1B + DEGB, B, 0, stream>>>(x, W1bt, H1b, col, ew, packed, rank);

    k_scan1<<<SCAN_BLOCKS, B, 0, stream>>>(packed, rowptr, bsum, dinv);
    k_scan3<<<SCAN_BLOCKS, B, 0, stream>>>(rowptr, bsum);

    k_scatter<<<SCATB, B, 0, stream>>>(row, col, ew, dinv, rowptr, rank, es);

    k_agg1_csr<<<(N_NODES + 3) / 4, B, 0, stream>>>(rowptr, es, dinv, H1b, b1, A1b);

    k_gemm2_mfma<<<(N_NODES + 127) / 128, B, 0, stream>>>(A1b, W2bt, H2b);

    k_agg2_lsm<<<(N_NODES + 3) / 4, B, 0, stream>>>(rowptr, es, dinv, H2b, b2, out);
}